// Round 1
// 639.253 us; speedup vs baseline: 1.1288x; 1.1288x over previous
//
#include <hip/hip_runtime.h>
#include <hip/hip_bf16.h>
#include <stdint.h>

#define NA 500000
#define NB 500000
#define EE 1000000
#define NBUCK 3907          // ceil(500000/128)
// Per-XCD slice capacities. 8 slices per bucket.
// famA: per-slice mean 64 (Poisson), cap 88 = +3 sigma; spill-chain + oflow beyond.
// famB: per-slice mean 32, cap 50 = +3.2 sigma.
#define SCAPA 88            // 8*88  = 704 entries/bucket (same total as before)
#define SCAPB 50            // 8*50  = 400 entries/bucket
#define OCAP 4096

__device__ __forceinline__ uint32_t f2bf(float f) {
    uint32_t b = __builtin_bit_cast(uint32_t, f);
    return (b + 0x7FFFu + ((b >> 16) & 1u)) >> 16;  // RNE
}

__device__ __forceinline__ int xcc_id() {
    int x;
    asm("s_getreg_b32 %0, hwreg(HW_REG_XCC_ID)" : "=s"(x));
    return x & 7;
}

// ---- K1: bucket scatter, XCD-sliced. entry = src | type<<19 | dstLocal<<20 ----
// Each (bucket, xcd) slice is written only by waves on that XCD -> each 64B
// frontier line fills inside one L2 and writes back once (kills the 13x
// partial-line write amplification seen in rocprof: WRITE_SIZE 151MB for 12MB).
__global__ __launch_bounds__(256) void bucket_scatter(
    const int* __restrict__ ei_ab, const int* __restrict__ ei_ba,
    const int* __restrict__ ei_aa,
    int* __restrict__ cnt_a, int* __restrict__ cnt_b,
    uint32_t* __restrict__ buck_a, uint32_t* __restrict__ buck_b,
    int* __restrict__ ocnt, uint2* __restrict__ oflow) {
    const int xcd = xcc_id();
    int gid = blockIdx.x * 256 + threadIdx.x;
    if (gid >= 3 * EE) return;
    int dst, src, type, famA;
    if (gid < EE) {                 // ab -> dst is b-node, src indexes xa/ta0
        dst = ei_ab[EE + gid]; src = ei_ab[gid]; type = 0; famA = 0;
    } else if (gid < 2 * EE) {      // ba -> dst a-node, src indexes xb/tb1
        int e = gid - EE;
        dst = ei_ba[EE + e]; src = ei_ba[e]; type = 0; famA = 1;
    } else {                        // aa -> dst a-node, src indexes xa/ta2
        int e = gid - 2 * EE;
        dst = ei_aa[EE + e]; src = ei_aa[e]; type = 1; famA = 1;
    }
    int bucket = dst >> 7;
    uint32_t entry = (uint32_t)src | ((uint32_t)type << 19) |
                     ((uint32_t)(dst & 127) << 20);
    int cap = famA ? SCAPA : SCAPB;
    int* cnt = famA ? cnt_a : cnt_b;
    uint32_t* buck = famA ? buck_a : buck_b;
    int slot = atomicAdd(&cnt[xcd * NBUCK + bucket], 1);
    if (slot < cap) {
        buck[((size_t)bucket * 8 + xcd) * cap + slot] = entry;
    } else {
        // Rare: own slice full. Probe the other 7 slices before giving up,
        // so total per-bucket capacity matches the old single-slice scheme
        // even under a skewed block->XCD mapping.
        bool placed = false;
        for (int d = 1; d < 8; ++d) {
            int s2 = (xcd + d) & 7;
            int sl2 = atomicAdd(&cnt[s2 * NBUCK + bucket], 1);
            if (sl2 < cap) {
                buck[((size_t)bucket * 8 + s2) * cap + sl2] = entry;
                placed = true;
                break;
            }
        }
        if (!placed) {
            int o = atomicAdd(ocnt, 1);
            if (o < OCAP)
                oflow[o] = make_uint2((uint32_t)dst | ((uint32_t)famA << 30) |
                                      ((uint32_t)type << 29), (uint32_t)src);
        }
    }
}

// ---- K2: per-bucket counting sort in LDS + layer-1 scalar aggregation ----
// Loads the 8 XCD slices concatenated, sorts by dst-local, compacts the
// sorted entries to the front of the bucket region, records total K in ktot.
__global__ __launch_bounds__(256) void sort_agg(
    const int* __restrict__ cnt_a, const int* __restrict__ cnt_b,
    uint32_t* __restrict__ buck_a, uint32_t* __restrict__ buck_b,
    const float* __restrict__ xa, const float* __restrict__ xb,
    float* __restrict__ agg_ba, float* __restrict__ agg_aa,
    float* __restrict__ agg_ab,
    uint16_t* __restrict__ start16_a, uint16_t* __restrict__ start16_b,
    uint16_t* __restrict__ ktot_a, uint16_t* __restrict__ ktot_b) {
    __shared__ uint32_t raw[8 * SCAPA];
    __shared__ uint32_t sorted[8 * SCAPA];
    __shared__ int hist[128], cursor[128], startS[128], fillC[128];
    __shared__ int offS[9];
    __shared__ float sAgg[256];
    const int bucket = blockIdx.x;
    const int isA = (blockIdx.y == 0);
    const int cap = isA ? SCAPA : SCAPB;
    const int* cnt = isA ? cnt_a : cnt_b;
    uint32_t* buckbase = (isA ? buck_a : buck_b) + (size_t)bucket * 8 * cap;
    const int t = threadIdx.x;
    if (t < 128) hist[t] = 0;
    sAgg[t] = 0.f;
    if (t == 0) {
        int acc = 0;
        offS[0] = 0;
        for (int s = 0; s < 8; ++s) {
            int c = cnt[s * NBUCK + bucket];
            c = c < cap ? c : cap;
            acc += c;
            offS[s + 1] = acc;
        }
    }
    __syncthreads();
    const int K = offS[8];
    for (int i = t; i < K; i += 256) {
        int s = 0;
        while (i >= offS[s + 1]) ++s;         // <=8 LDS probes, no scratch
        uint32_t e = buckbase[s * cap + (i - offS[s])];
        raw[i] = e;
        atomicAdd(&hist[e >> 20], 1);
    }
    __syncthreads();
    // inclusive scan of hist -> cursor
    if (t < 128) cursor[t] = hist[t];
    __syncthreads();
    for (int off = 1; off < 128; off <<= 1) {
        int v = 0;
        if (t < 128) { v = cursor[t]; if (t >= off) v += cursor[t - off]; }
        __syncthreads();
        if (t < 128) cursor[t] = v;
        __syncthreads();
    }
    if (t < 128) {
        int st = cursor[t] - hist[t];   // exclusive
        startS[t] = st;
        fillC[t] = st;
    }
    __syncthreads();
    // place + aggregate
    for (int i = t; i < K; i += 256) {
        uint32_t e = raw[i];
        int loc = e >> 20;
        int type = (e >> 19) & 1;
        int src = e & 0x7FFFF;
        int pos = atomicAdd(&fillC[loc], 1);
        sorted[pos] = e;
        float xv = isA ? (type ? xa[src] : xb[src]) : xa[src];
        atomicAdd(&sAgg[loc * 2 + type], xv);
    }
    __syncthreads();
    // compact sorted entries to front of bucket region
    for (int i = t; i < K; i += 256) buckbase[i] = sorted[i];
    if (t == 0) {
        if (isA) ktot_a[bucket] = (uint16_t)K;
        else     ktot_b[bucket] = (uint16_t)K;
    }
    if (t < 128) {
        int n = bucket * 128 + t;
        if (isA) {
            start16_a[bucket * 128 + t] = (uint16_t)startS[t];
            if (n < NA) {
                agg_ba[n] = sAgg[t * 2];
                agg_aa[n] = sAgg[t * 2 + 1];
            }
        } else {
            start16_b[bucket * 128 + t] = (uint16_t)startS[t];
            if (n < NB) agg_ab[n] = sAgg[t * 2];
        }
    }
}

// ---- K2b: overflow agg fixup (normally ~zero iterations) ----
__global__ __launch_bounds__(256) void oflow_agg(
    const int* __restrict__ ocnt, const uint2* __restrict__ oflow,
    const float* __restrict__ xa, const float* __restrict__ xb,
    float* __restrict__ agg_ba, float* __restrict__ agg_aa,
    float* __restrict__ agg_ab) {
    int n = *ocnt;
    n = n < OCAP ? n : OCAP;
    for (int i = threadIdx.x; i < n; i += 256) {
        uint2 r = oflow[i];
        int dst = r.x & 0x1FFFFFFF;
        int famA = (r.x >> 30) & 1;
        int type = (r.x >> 29) & 1;
        int src = (int)r.y;
        if (famA) {
            if (type) atomicAdd(&agg_aa[dst], xa[src]);
            else      atomicAdd(&agg_ba[dst], xb[src]);
        } else {
            atomicAdd(&agg_ab[dst], xa[src]);
        }
    }
}

// ---- K5: overflow out fixup (after gather; normally ~zero iterations) ----
__global__ __launch_bounds__(256) void oflow_out(
    const int* __restrict__ ocnt, const uint2* __restrict__ oflow,
    const uint16_t* __restrict__ ta0, const uint16_t* __restrict__ ta2,
    const uint16_t* __restrict__ tb1,
    float* __restrict__ outa, float* __restrict__ outb) {
    int n = *ocnt;
    n = n < OCAP ? n : OCAP;
    for (int i = threadIdx.x; i < n; i += 256) {
        uint2 r = oflow[i];
        int dst = r.x & 0x1FFFFFFF;
        int famA = (r.x >> 30) & 1;
        int type = (r.x >> 29) & 1;
        int src = (int)r.y;
        const uint16_t* tp = famA ? (type ? ta2 : tb1) : ta0;
        float* out = famA ? outa : outb;
        for (int k = 0; k < 32; ++k) {
            float v = __builtin_bit_cast(float,
                          (uint32_t)tp[(size_t)src * 32 + k] << 16);
            atomicAdd(&out[(size_t)dst * 32 + k], v);
        }
    }
}

// ---- K4: gather, 8 lanes per dst node ----
__global__ __launch_bounds__(256) void gather_out(
    const uint16_t* __restrict__ ktot_a, const uint16_t* __restrict__ ktot_b,
    const uint16_t* __restrict__ start16_a, const uint16_t* __restrict__ start16_b,
    const uint32_t* __restrict__ buck_a, const uint32_t* __restrict__ buck_b,
    const uint16_t* __restrict__ ta0, const uint16_t* __restrict__ ta2,
    const uint16_t* __restrict__ tb1,
    float* __restrict__ outa, float* __restrict__ outb) {
    int gid = blockIdx.x * 256 + threadIdx.x;   // exactly (NA+NB)*8 threads
    int n3 = gid >> 3;
    int l = gid & 7;
    float4 acc = make_float4(0.f, 0.f, 0.f, 0.f);
    if (n3 < NA) {
        int bucket = n3 >> 7, local = n3 & 127;
        int start = start16_a[n3];
        int end;
        if (local == 127) end = ktot_a[bucket];
        else              end = start16_a[n3 + 1];
        const uint32_t* bp = buck_a + (size_t)bucket * (8 * SCAPA);
        for (int i = start; i < end; ++i) {
            uint32_t e = bp[i];
            int src = e & 0x7FFFF;
            const uint16_t* tp = (e & (1u << 19)) ? ta2 : tb1;
            uint2 u = *(const uint2*)(tp + (size_t)src * 32 + l * 4);
            acc.x += __builtin_bit_cast(float, u.x << 16);
            acc.y += __builtin_bit_cast(float, u.x & 0xFFFF0000u);
            acc.z += __builtin_bit_cast(float, u.y << 16);
            acc.w += __builtin_bit_cast(float, u.y & 0xFFFF0000u);
        }
        float4* po = (float4*)(outa + (size_t)n3 * 32 + l * 4);
        float4 cur = *po;
        *po = make_float4(cur.x + acc.x, cur.y + acc.y, cur.z + acc.z, cur.w + acc.w);
    } else {
        int n = n3 - NA;
        int bucket = n >> 7, local = n & 127;
        int start = start16_b[n];
        int end;
        if (local == 127) end = ktot_b[bucket];
        else              end = start16_b[n + 1];
        const uint32_t* bp = buck_b + (size_t)bucket * (8 * SCAPB);
        for (int i = start; i < end; ++i) {
            uint32_t e = bp[i];
            int src = e & 0x7FFFF;
            uint2 u = *(const uint2*)(ta0 + (size_t)src * 32 + l * 4);
            acc.x += __builtin_bit_cast(float, u.x << 16);
            acc.y += __builtin_bit_cast(float, u.x & 0xFFFF0000u);
            acc.z += __builtin_bit_cast(float, u.y << 16);
            acc.w += __builtin_bit_cast(float, u.y & 0xFFFF0000u);
        }
        float4* po = (float4*)(outb + (size_t)n * 32 + l * 4);
        float4 cur = *po;
        *po = make_float4(cur.x + acc.x, cur.y + acc.y, cur.z + acc.z, cur.w + acc.w);
    }
}

// =================== node A (unchanged) ===================
__global__ __launch_bounds__(256) void node_a_kernel(
    const float* __restrict__ xa,
    const float* __restrict__ s_ba, const float* __restrict__ s_aa,
    const float* __restrict__ Wrel1, const float* __restrict__ Wroot1,
    const float* __restrict__ b1,
    const float* __restrict__ Wrel2, const float* __restrict__ Wroot2,
    const float* __restrict__ b2,
    uint16_t* __restrict__ ta0, uint16_t* __restrict__ ta2,
    float* __restrict__ outa) {
    __shared__ float uS[64], vS[64], wS[64], cS[64], bbS[32];
    __shared__ float W0[2048], W2[2048], WrS[2048];
    __shared__ uint32_t stageU[4352];
    float* stageF = (float*)stageU;
    const int t = threadIdx.x;
    if (t < 64) {
        uS[t] = Wrel1[64 + t];
        vS[t] = Wrel1[128 + t];
        wS[t] = Wroot1[64 + t] + Wroot1[128 + t];
        cS[t] = b1[64 + t] + b1[128 + t];
    }
    if (t >= 64 && t < 96) bbS[t - 64] = b2[32 + (t - 64)] + b2[64 + (t - 64)];
    for (int i = t; i < 2048; i += 256) {
        W0[i]  = Wrel2[i];
        W2[i]  = Wrel2[4096 + i];
        WrS[i] = Wroot2[2048 + i] + Wroot2[4096 + i];
    }
    __syncthreads();

    const int blk = blockIdx.x;
    const int n = blk * 256 + t;
    const bool valid = (n < NA);
    const int validN = (NA - blk * 256) < 256 ? (NA - blk * 256) : 256;
    float sba = 0.f, saa = 0.f, x = 0.f;
    if (valid) { sba = s_ba[n]; saa = s_aa[n]; x = xa[n]; }

    float a0[32], a2[32];
#pragma unroll
    for (int o = 0; o < 32; ++o) { a0[o] = 0.f; a2[o] = 0.f; }
#pragma unroll 2
    for (int j = 0; j < 64; ++j) {
        float hj = fmaxf(fmaf(sba, uS[j], fmaf(saa, vS[j], fmaf(x, wS[j], cS[j]))), 0.f);
        const float4* w0 = (const float4*)(&W0[j * 32]);
        const float4* w2 = (const float4*)(&W2[j * 32]);
#pragma unroll
        for (int q = 0; q < 8; ++q) {
            float4 v0 = w0[q], v2 = w2[q];
            a0[q * 4 + 0] = fmaf(hj, v0.x, a0[q * 4 + 0]);
            a0[q * 4 + 1] = fmaf(hj, v0.y, a0[q * 4 + 1]);
            a0[q * 4 + 2] = fmaf(hj, v0.z, a0[q * 4 + 2]);
            a0[q * 4 + 3] = fmaf(hj, v0.w, a0[q * 4 + 3]);
            a2[q * 4 + 0] = fmaf(hj, v2.x, a2[q * 4 + 0]);
            a2[q * 4 + 1] = fmaf(hj, v2.y, a2[q * 4 + 1]);
            a2[q * 4 + 2] = fmaf(hj, v2.z, a2[q * 4 + 2]);
            a2[q * 4 + 3] = fmaf(hj, v2.w, a2[q * 4 + 3]);
        }
    }

    if (valid) {
#pragma unroll
        for (int k = 0; k < 16; ++k)
            stageU[t * 17 + k] = f2bf(a0[2 * k]) | (f2bf(a0[2 * k + 1]) << 16);
    }
    __syncthreads();
#pragma unroll
    for (int it = 0; it < 4; ++it) {
        int idx4 = t + 256 * it;
        if (idx4 < validN * 4) {
            int node = idx4 >> 2, q = (idx4 & 3) * 4;
            uint4 v = make_uint4(stageU[node * 17 + q], stageU[node * 17 + q + 1],
                                 stageU[node * 17 + q + 2], stageU[node * 17 + q + 3]);
            ((uint4*)ta0)[(size_t)blk * 1024 + idx4] = v;
        }
    }
    __syncthreads();
    if (valid) {
#pragma unroll
        for (int k = 0; k < 16; ++k)
            stageU[t * 17 + k] = f2bf(a2[2 * k]) | (f2bf(a2[2 * k + 1]) << 16);
    }
    __syncthreads();
#pragma unroll
    for (int it = 0; it < 4; ++it) {
        int idx4 = t + 256 * it;
        if (idx4 < validN * 4) {
            int node = idx4 >> 2, q = (idx4 & 3) * 4;
            uint4 v = make_uint4(stageU[node * 17 + q], stageU[node * 17 + q + 1],
                                 stageU[node * 17 + q + 2], stageU[node * 17 + q + 3]);
            ((uint4*)ta2)[(size_t)blk * 1024 + idx4] = v;
        }
    }

    float aR[32];
#pragma unroll
    for (int o = 0; o < 32; ++o) aR[o] = bbS[o];
#pragma unroll 2
    for (int j = 0; j < 64; ++j) {
        float hj = fmaxf(fmaf(sba, uS[j], fmaf(saa, vS[j], fmaf(x, wS[j], cS[j]))), 0.f);
        const float4* wr = (const float4*)(&WrS[j * 32]);
#pragma unroll
        for (int q = 0; q < 8; ++q) {
            float4 wv = wr[q];
            aR[q * 4 + 0] = fmaf(hj, wv.x, aR[q * 4 + 0]);
            aR[q * 4 + 1] = fmaf(hj, wv.y, aR[q * 4 + 1]);
            aR[q * 4 + 2] = fmaf(hj, wv.z, aR[q * 4 + 2]);
            aR[q * 4 + 3] = fmaf(hj, wv.w, aR[q * 4 + 3]);
        }
    }
#pragma unroll 1
    for (int p = 0; p < 2; ++p) {
        __syncthreads();
        int l = t - p * 128;
        if (l >= 0 && l < 128 && valid) {
#pragma unroll
            for (int k = 0; k < 32; ++k) stageF[l * 33 + k] = aR[k];
        }
        __syncthreads();
        int remN = NA - blk * 256 - p * 128;
        int validNp = remN < 0 ? 0 : (remN > 128 ? 128 : remN);
#pragma unroll
        for (int it = 0; it < 4; ++it) {
            int idx4 = t + 256 * it;
            if (idx4 < validNp * 8) {
                int node = idx4 >> 3, q = (idx4 & 7) * 4;
                float4 v = make_float4(stageF[node * 33 + q], stageF[node * 33 + q + 1],
                                       stageF[node * 33 + q + 2], stageF[node * 33 + q + 3]);
                ((float4*)outa)[(size_t)blk * 2048 + p * 1024 + idx4] = v;
            }
        }
    }
}

// =================== node B (unchanged) ===================
__global__ __launch_bounds__(256) void node_b_kernel(
    const float* __restrict__ xb, const float* __restrict__ s_ab,
    const float* __restrict__ Wrel1, const float* __restrict__ Wroot1,
    const float* __restrict__ b1,
    const float* __restrict__ Wrel2, const float* __restrict__ Wroot2,
    const float* __restrict__ b2,
    uint16_t* __restrict__ tb1, float* __restrict__ outb) {
    __shared__ float uS[64], wS[64], cS[64], bbS[32];
    __shared__ float W1[2048], WrS[2048];
    __shared__ uint32_t stageU[4352];
    float* stageF = (float*)stageU;
    const int t = threadIdx.x;
    if (t < 64) {
        uS[t] = Wrel1[t];
        wS[t] = Wroot1[t];
        cS[t] = b1[t];
    }
    if (t >= 64 && t < 96) bbS[t - 64] = b2[t - 64];
    for (int i = t; i < 2048; i += 256) {
        W1[i]  = Wrel2[2048 + i];
        WrS[i] = Wroot2[i];
    }
    __syncthreads();

    const int blk = blockIdx.x;
    const int n = blk * 256 + t;
    const bool valid = (n < NB);
    const int validN = (NB - blk * 256) < 256 ? (NB - blk * 256) : 256;
    float sab = 0.f, x = 0.f;
    if (valid) { sab = s_ab[n]; x = xb[n]; }

    float a1[32], aR[32];
#pragma unroll
    for (int o = 0; o < 32; ++o) { a1[o] = 0.f; aR[o] = bbS[o]; }
#pragma unroll 2
    for (int j = 0; j < 64; ++j) {
        float hj = fmaxf(fmaf(sab, uS[j], fmaf(x, wS[j], cS[j])), 0.f);
        const float4* w1 = (const float4*)(&W1[j * 32]);
        const float4* wr = (const float4*)(&WrS[j * 32]);
#pragma unroll
        for (int q = 0; q < 8; ++q) {
            float4 v1 = w1[q], vr = wr[q];
            a1[q * 4 + 0] = fmaf(hj, v1.x, a1[q * 4 + 0]);
            a1[q * 4 + 1] = fmaf(hj, v1.y, a1[q * 4 + 1]);
            a1[q * 4 + 2] = fmaf(hj, v1.z, a1[q * 4 + 2]);
            a1[q * 4 + 3] = fmaf(hj, v1.w, a1[q * 4 + 3]);
            aR[q * 4 + 0] = fmaf(hj, vr.x, aR[q * 4 + 0]);
            aR[q * 4 + 1] = fmaf(hj, vr.y, aR[q * 4 + 1]);
            aR[q * 4 + 2] = fmaf(hj, vr.z, aR[q * 4 + 2]);
            aR[q * 4 + 3] = fmaf(hj, vr.w, aR[q * 4 + 3]);
        }
    }

    if (valid) {
#pragma unroll
        for (int k = 0; k < 16; ++k)
            stageU[t * 17 + k] = f2bf(a1[2 * k]) | (f2bf(a1[2 * k + 1]) << 16);
    }
    __syncthreads();
#pragma unroll
    for (int it = 0; it < 4; ++it) {
        int idx4 = t + 256 * it;
        if (idx4 < validN * 4) {
            int node = idx4 >> 2, q = (idx4 & 3) * 4;
            uint4 v = make_uint4(stageU[node * 17 + q], stageU[node * 17 + q + 1],
                                 stageU[node * 17 + q + 2], stageU[node * 17 + q + 3]);
            ((uint4*)tb1)[(size_t)blk * 1024 + idx4] = v;
        }
    }

#pragma unroll 1
    for (int p = 0; p < 2; ++p) {
        __syncthreads();
        int l = t - p * 128;
        if (l >= 0 && l < 128 && valid) {
#pragma unroll
            for (int k = 0; k < 32; ++k) stageF[l * 33 + k] = aR[k];
        }
        __syncthreads();
        int remN = NB - blk * 256 - p * 128;
        int validNp = remN < 0 ? 0 : (remN > 128 ? 128 : remN);
#pragma unroll
        for (int it = 0; it < 4; ++it) {
            int idx4 = t + 256 * it;
            if (idx4 < validNp * 8) {
                int node = idx4 >> 3, q = (idx4 & 7) * 4;
                float4 v = make_float4(stageF[node * 33 + q], stageF[node * 33 + q + 1],
                                       stageF[node * 33 + q + 2], stageF[node * 33 + q + 3]);
                ((float4*)outb)[(size_t)blk * 2048 + p * 1024 + idx4] = v;
            }
        }
    }
}

extern "C" void kernel_launch(void* const* d_in, const int* in_sizes, int n_in,
                              void* d_out, int out_size, void* d_ws, size_t ws_size,
                              hipStream_t stream) {
    const float* x_a    = (const float*)d_in[0];
    const float* x_b    = (const float*)d_in[1];
    const int*   ei_ab  = (const int*)d_in[2];
    const int*   ei_ba  = (const int*)d_in[3];
    const int*   ei_aa  = (const int*)d_in[4];
    const float* Wrel1  = (const float*)d_in[5];
    const float* Wroot1 = (const float*)d_in[6];
    const float* b1     = (const float*)d_in[7];
    const float* Wrel2  = (const float*)d_in[8];
    const float* Wroot2 = (const float*)d_in[9];
    const float* b2     = (const float*)d_in[10];

    float* outa = (float*)d_out;                       // [NA,32]
    float* outb = (float*)d_out + (size_t)NA * 32;     // [NB,32]

    char* ws = (char*)d_ws;
    // Layout (bytes):
    uint32_t* buck_a   = (uint32_t*)(ws);                    // 3907*704*4  = 11,002,112
    uint32_t* buck_b   = (uint32_t*)(ws + 11002112);         // 3907*400*4  =  6,251,200
    float*    agg_ba   = (float*)(ws + 17253312);            // NA floats   =  2,000,000
    float*    agg_aa   = (float*)(ws + 19253312);            // NA floats
    float*    agg_ab   = (float*)(ws + 21253312);            // NB floats
    uint16_t* ta0      = (uint16_t*)(ws + 23253312);         // NA*32 bf16  = 32,000,000
    uint16_t* ta2      = (uint16_t*)(ws + 55253312);         // NA*32 bf16
    uint16_t* tb1      = (uint16_t*)(ws + 87253312);         // NB*32 bf16
    uint16_t* start16_a= (uint16_t*)(ws + 119253312);        // 3907*128 u16 = 1,000,192
    uint16_t* start16_b= (uint16_t*)(ws + 120253504);        // 3907*128 u16
    uint16_t* ktot_a   = (uint16_t*)(ws + 121253696);        // 3907 u16 (pad 8192)
    uint16_t* ktot_b   = (uint16_t*)(ws + 121261888);        // 3907 u16 (pad 8192)
    int*      cnt_a    = (int*)(ws + 121270080);             // 8*3907 int = 125,024
    int*      cnt_b    = (int*)(ws + 121395104);             // 8*3907 int
    int*      ocnt     = (int*)(ws + 121520128);             // 1 int (+4 pad)
    uint2*    oflow    = (uint2*)(ws + 121520136);           // 4096 uint2 = 32,768
    if (ws_size < 121560000) return;  // need ~121.56 MB scratch

    // zero cnt_a, cnt_b, ocnt (one contiguous span)
    hipMemsetAsync((char*)cnt_a, 0, 125024 + 125024 + 8, stream);

    dim3 blk(256);
    int egrid = (3 * EE + 255) / 256;
    bucket_scatter<<<egrid, blk, 0, stream>>>(ei_ab, ei_ba, ei_aa, cnt_a, cnt_b,
                                              buck_a, buck_b, ocnt, oflow);

    sort_agg<<<dim3(NBUCK, 2), blk, 0, stream>>>(cnt_a, cnt_b, buck_a, buck_b,
                                                 x_a, x_b, agg_ba, agg_aa, agg_ab,
                                                 start16_a, start16_b,
                                                 ktot_a, ktot_b);
    oflow_agg<<<1, blk, 0, stream>>>(ocnt, oflow, x_a, x_b, agg_ba, agg_aa, agg_ab);

    int ngrid = (NA + 255) / 256;
    node_a_kernel<<<ngrid, blk, 0, stream>>>(x_a, agg_ba, agg_aa, Wrel1, Wroot1,
                                             b1, Wrel2, Wroot2, b2, ta0, ta2, outa);
    node_b_kernel<<<ngrid, blk, 0, stream>>>(x_b, agg_ab, Wrel1, Wroot1, b1,
                                             Wrel2, Wroot2, b2, tb1, outb);

    int ggrid = (int)(((size_t)(NA + NB) * 8) / 256);  // 31250 exact
    gather_out<<<ggrid, blk, 0, stream>>>(ktot_a, ktot_b, start16_a, start16_b,
                                          buck_a, buck_b, ta0, ta2, tb1,
                                          outa, outb);
    oflow_out<<<1, blk, 0, stream>>>(ocnt, oflow, ta0, ta2, tb1, outa, outb);
}

// Round 2
// 559.923 us; speedup vs baseline: 1.2888x; 1.1417x over previous
//
#include <hip/hip_runtime.h>
#include <hip/hip_bf16.h>
#include <stdint.h>

#define NA 500000
#define NB 500000
#define EE 1000000
#define NBUCK 3907          // ceil(500000/128)
// Per-XCD slice capacities. 8 slices per bucket.
#define SCAPA 88            // 8*88  = 704 entries/bucket
#define SCAPB 50            // 8*50  = 400 entries/bucket
#define OCAP 4096
#define NPT 4               // nodes per thread in node kernels

__device__ __forceinline__ uint32_t f2bf(float f) {
    uint32_t b = __builtin_bit_cast(uint32_t, f);
    return (b + 0x7FFFu + ((b >> 16) & 1u)) >> 16;  // RNE
}

__device__ __forceinline__ int xcc_id() {
    int x;
    asm("s_getreg_b32 %0, hwreg(HW_REG_XCC_ID)" : "=s"(x));
    return x & 7;
}

// ---- K1: bucket scatter, XCD-sliced. entry = src | type<<19 | dstLocal<<20 ----
__global__ __launch_bounds__(256) void bucket_scatter(
    const int* __restrict__ ei_ab, const int* __restrict__ ei_ba,
    const int* __restrict__ ei_aa,
    int* __restrict__ cnt_a, int* __restrict__ cnt_b,
    uint32_t* __restrict__ buck_a, uint32_t* __restrict__ buck_b,
    int* __restrict__ ocnt, uint2* __restrict__ oflow) {
    const int xcd = xcc_id();
    int gid = blockIdx.x * 256 + threadIdx.x;
    if (gid >= 3 * EE) return;
    int dst, src, type, famA;
    if (gid < EE) {                 // ab -> dst is b-node, src indexes xa/ta0
        dst = ei_ab[EE + gid]; src = ei_ab[gid]; type = 0; famA = 0;
    } else if (gid < 2 * EE) {      // ba -> dst a-node, src indexes xb/tb1
        int e = gid - EE;
        dst = ei_ba[EE + e]; src = ei_ba[e]; type = 0; famA = 1;
    } else {                        // aa -> dst a-node, src indexes xa/ta2
        int e = gid - 2 * EE;
        dst = ei_aa[EE + e]; src = ei_aa[e]; type = 1; famA = 1;
    }
    int bucket = dst >> 7;
    uint32_t entry = (uint32_t)src | ((uint32_t)type << 19) |
                     ((uint32_t)(dst & 127) << 20);
    int cap = famA ? SCAPA : SCAPB;
    int* cnt = famA ? cnt_a : cnt_b;
    uint32_t* buck = famA ? buck_a : buck_b;
    int slot = atomicAdd(&cnt[xcd * NBUCK + bucket], 1);
    if (slot < cap) {
        buck[((size_t)bucket * 8 + xcd) * cap + slot] = entry;
    } else {
        bool placed = false;
        for (int d = 1; d < 8; ++d) {
            int s2 = (xcd + d) & 7;
            int sl2 = atomicAdd(&cnt[s2 * NBUCK + bucket], 1);
            if (sl2 < cap) {
                buck[((size_t)bucket * 8 + s2) * cap + sl2] = entry;
                placed = true;
                break;
            }
        }
        if (!placed) {
            int o = atomicAdd(ocnt, 1);
            if (o < OCAP)
                oflow[o] = make_uint2((uint32_t)dst | ((uint32_t)famA << 30) |
                                      ((uint32_t)type << 29), (uint32_t)src);
        }
    }
}

// ---- K2: per-bucket counting sort in LDS + layer-1 scalar aggregation ----
__global__ __launch_bounds__(256) void sort_agg(
    const int* __restrict__ cnt_a, const int* __restrict__ cnt_b,
    uint32_t* __restrict__ buck_a, uint32_t* __restrict__ buck_b,
    const float* __restrict__ xa, const float* __restrict__ xb,
    float* __restrict__ agg_ba, float* __restrict__ agg_aa,
    float* __restrict__ agg_ab,
    uint16_t* __restrict__ start16_a, uint16_t* __restrict__ start16_b,
    uint16_t* __restrict__ ktot_a, uint16_t* __restrict__ ktot_b) {
    __shared__ uint32_t raw[8 * SCAPA];
    __shared__ uint32_t sorted[8 * SCAPA];
    __shared__ int hist[128], cursor[128], startS[128], fillC[128];
    __shared__ int offS[9];
    __shared__ float sAgg[256];
    const int bucket = blockIdx.x;
    const int isA = (blockIdx.y == 0);
    const int cap = isA ? SCAPA : SCAPB;
    const int* cnt = isA ? cnt_a : cnt_b;
    uint32_t* buckbase = (isA ? buck_a : buck_b) + (size_t)bucket * 8 * cap;
    const int t = threadIdx.x;
    if (t < 128) hist[t] = 0;
    sAgg[t] = 0.f;
    if (t == 0) {
        int acc = 0;
        offS[0] = 0;
        for (int s = 0; s < 8; ++s) {
            int c = cnt[s * NBUCK + bucket];
            c = c < cap ? c : cap;
            acc += c;
            offS[s + 1] = acc;
        }
    }
    __syncthreads();
    const int K = offS[8];
    for (int i = t; i < K; i += 256) {
        int s = 0;
        while (i >= offS[s + 1]) ++s;         // <=8 LDS probes, no scratch
        uint32_t e = buckbase[s * cap + (i - offS[s])];
        raw[i] = e;
        atomicAdd(&hist[e >> 20], 1);
    }
    __syncthreads();
    // inclusive scan of hist -> cursor
    if (t < 128) cursor[t] = hist[t];
    __syncthreads();
    for (int off = 1; off < 128; off <<= 1) {
        int v = 0;
        if (t < 128) { v = cursor[t]; if (t >= off) v += cursor[t - off]; }
        __syncthreads();
        if (t < 128) cursor[t] = v;
        __syncthreads();
    }
    if (t < 128) {
        int st = cursor[t] - hist[t];   // exclusive
        startS[t] = st;
        fillC[t] = st;
    }
    __syncthreads();
    // place + aggregate
    for (int i = t; i < K; i += 256) {
        uint32_t e = raw[i];
        int loc = e >> 20;
        int type = (e >> 19) & 1;
        int src = e & 0x7FFFF;
        int pos = atomicAdd(&fillC[loc], 1);
        sorted[pos] = e;
        float xv = isA ? (type ? xa[src] : xb[src]) : xa[src];
        atomicAdd(&sAgg[loc * 2 + type], xv);
    }
    __syncthreads();
    // compact sorted entries to front of bucket region
    for (int i = t; i < K; i += 256) buckbase[i] = sorted[i];
    if (t == 0) {
        if (isA) ktot_a[bucket] = (uint16_t)K;
        else     ktot_b[bucket] = (uint16_t)K;
    }
    if (t < 128) {
        int n = bucket * 128 + t;
        if (isA) {
            start16_a[bucket * 128 + t] = (uint16_t)startS[t];
            if (n < NA) {
                agg_ba[n] = sAgg[t * 2];
                agg_aa[n] = sAgg[t * 2 + 1];
            }
        } else {
            start16_b[bucket * 128 + t] = (uint16_t)startS[t];
            if (n < NB) agg_ab[n] = sAgg[t * 2];
        }
    }
}

// ---- K2b: overflow agg fixup (normally ~zero iterations) ----
__global__ __launch_bounds__(256) void oflow_agg(
    const int* __restrict__ ocnt, const uint2* __restrict__ oflow,
    const float* __restrict__ xa, const float* __restrict__ xb,
    float* __restrict__ agg_ba, float* __restrict__ agg_aa,
    float* __restrict__ agg_ab) {
    int n = *ocnt;
    n = n < OCAP ? n : OCAP;
    for (int i = threadIdx.x; i < n; i += 256) {
        uint2 r = oflow[i];
        int dst = r.x & 0x1FFFFFFF;
        int famA = (r.x >> 30) & 1;
        int type = (r.x >> 29) & 1;
        int src = (int)r.y;
        if (famA) {
            if (type) atomicAdd(&agg_aa[dst], xa[src]);
            else      atomicAdd(&agg_ba[dst], xb[src]);
        } else {
            atomicAdd(&agg_ab[dst], xa[src]);
        }
    }
}

// ---- K5: overflow out fixup (after gather; normally ~zero iterations) ----
__global__ __launch_bounds__(256) void oflow_out(
    const int* __restrict__ ocnt, const uint2* __restrict__ oflow,
    const uint16_t* __restrict__ ta0, const uint16_t* __restrict__ ta2,
    const uint16_t* __restrict__ tb1,
    float* __restrict__ outa, float* __restrict__ outb) {
    int n = *ocnt;
    n = n < OCAP ? n : OCAP;
    for (int i = threadIdx.x; i < n; i += 256) {
        uint2 r = oflow[i];
        int dst = r.x & 0x1FFFFFFF;
        int famA = (r.x >> 30) & 1;
        int type = (r.x >> 29) & 1;
        int src = (int)r.y;
        const uint16_t* tp = famA ? (type ? ta2 : tb1) : ta0;
        float* out = famA ? outa : outb;
        for (int k = 0; k < 32; ++k) {
            float v = __builtin_bit_cast(float,
                          (uint32_t)tp[(size_t)src * 32 + k] << 16);
            atomicAdd(&out[(size_t)dst * 32 + k], v);
        }
    }
}

// ---- K4: gather, 8 lanes per dst node ----
__global__ __launch_bounds__(256) void gather_out(
    const uint16_t* __restrict__ ktot_a, const uint16_t* __restrict__ ktot_b,
    const uint16_t* __restrict__ start16_a, const uint16_t* __restrict__ start16_b,
    const uint32_t* __restrict__ buck_a, const uint32_t* __restrict__ buck_b,
    const uint16_t* __restrict__ ta0, const uint16_t* __restrict__ ta2,
    const uint16_t* __restrict__ tb1,
    float* __restrict__ outa, float* __restrict__ outb) {
    int gid = blockIdx.x * 256 + threadIdx.x;   // exactly (NA+NB)*8 threads
    int n3 = gid >> 3;
    int l = gid & 7;
    float4 acc = make_float4(0.f, 0.f, 0.f, 0.f);
    if (n3 < NA) {
        int bucket = n3 >> 7, local = n3 & 127;
        int start = start16_a[n3];
        int end;
        if (local == 127) end = ktot_a[bucket];
        else              end = start16_a[n3 + 1];
        const uint32_t* bp = buck_a + (size_t)bucket * (8 * SCAPA);
        for (int i = start; i < end; ++i) {
            uint32_t e = bp[i];
            int src = e & 0x7FFFF;
            const uint16_t* tp = (e & (1u << 19)) ? ta2 : tb1;
            uint2 u = *(const uint2*)(tp + (size_t)src * 32 + l * 4);
            acc.x += __builtin_bit_cast(float, u.x << 16);
            acc.y += __builtin_bit_cast(float, u.x & 0xFFFF0000u);
            acc.z += __builtin_bit_cast(float, u.y << 16);
            acc.w += __builtin_bit_cast(float, u.y & 0xFFFF0000u);
        }
        float4* po = (float4*)(outa + (size_t)n3 * 32 + l * 4);
        float4 cur = *po;
        *po = make_float4(cur.x + acc.x, cur.y + acc.y, cur.z + acc.z, cur.w + acc.w);
    } else {
        int n = n3 - NA;
        int bucket = n >> 7, local = n & 127;
        int start = start16_b[n];
        int end;
        if (local == 127) end = ktot_b[bucket];
        else              end = start16_b[n + 1];
        const uint32_t* bp = buck_b + (size_t)bucket * (8 * SCAPB);
        for (int i = start; i < end; ++i) {
            uint32_t e = bp[i];
            int src = e & 0x7FFFF;
            uint2 u = *(const uint2*)(ta0 + (size_t)src * 32 + l * 4);
            acc.x += __builtin_bit_cast(float, u.x << 16);
            acc.y += __builtin_bit_cast(float, u.x & 0xFFFF0000u);
            acc.z += __builtin_bit_cast(float, u.y << 16);
            acc.w += __builtin_bit_cast(float, u.y & 0xFFFF0000u);
        }
        float4* po = (float4*)(outb + (size_t)n * 32 + l * 4);
        float4 cur = *po;
        *po = make_float4(cur.x + acc.x, cur.y + acc.y, cur.z + acc.z, cur.w + acc.w);
    }
}

// ---------- shared staging helpers for node kernels ----------
// Pack NPT rounds of 256 nodes' 32 bf16 outputs via LDS, coalesced uint4 writes.
#define STAGE_BF16(ACC, DSTPTR, NTOT)                                        \
    _Pragma("unroll")                                                        \
    for (int r = 0; r < NPT; ++r) {                                          \
        __syncthreads();                                                     \
        int n0_ = base + r * 256;                                            \
        if (n0_ + t < (NTOT)) {                                              \
            _Pragma("unroll")                                                \
            for (int k = 0; k < 16; ++k)                                     \
                stageU[t * 17 + k] = f2bf(ACC[r][2 * k]) |                   \
                                     (f2bf(ACC[r][2 * k + 1]) << 16);        \
        }                                                                    \
        __syncthreads();                                                     \
        int vN_ = (NTOT) - n0_;                                              \
        vN_ = vN_ < 0 ? 0 : (vN_ > 256 ? 256 : vN_);                         \
        _Pragma("unroll")                                                    \
        for (int it = 0; it < 4; ++it) {                                     \
            int idx4 = t + 256 * it;                                         \
            if (idx4 < vN_ * 4) {                                            \
                int node = idx4 >> 2, q = (idx4 & 3) * 4;                    \
                uint4 v = make_uint4(stageU[node * 17 + q],                  \
                                     stageU[node * 17 + q + 1],              \
                                     stageU[node * 17 + q + 2],              \
                                     stageU[node * 17 + q + 3]);             \
                ((uint4*)(DSTPTR))[(size_t)n0_ * 4 + idx4] = v;              \
            }                                                                \
        }                                                                    \
    }

#define STAGE_F32(ACC, DSTPTR, NTOT)                                         \
    _Pragma("unroll")                                                        \
    for (int r = 0; r < NPT; ++r) {                                          \
        _Pragma("unroll")                                                    \
        for (int p = 0; p < 2; ++p) {                                        \
            __syncthreads();                                                 \
            int l_ = t - p * 128;                                            \
            int n0_ = base + r * 256;                                        \
            if (l_ >= 0 && l_ < 128 && (n0_ + t) < (NTOT)) {                 \
                _Pragma("unroll")                                            \
                for (int k = 0; k < 32; ++k)                                 \
                    stageF[l_ * 33 + k] = ACC[r][k];                         \
            }                                                                \
            __syncthreads();                                                 \
            int rem_ = (NTOT) - n0_ - p * 128;                               \
            int vNp_ = rem_ < 0 ? 0 : (rem_ > 128 ? 128 : rem_);             \
            _Pragma("unroll")                                                \
            for (int it = 0; it < 4; ++it) {                                 \
                int idx4 = t + 256 * it;                                     \
                if (idx4 < vNp_ * 8) {                                       \
                    int node = idx4 >> 3, q = (idx4 & 7) * 4;                \
                    float4 v = make_float4(stageF[node * 33 + q],            \
                                           stageF[node * 33 + q + 1],        \
                                           stageF[node * 33 + q + 2],        \
                                           stageF[node * 33 + q + 3]);       \
                    ((float4*)(DSTPTR))[(size_t)(n0_ + p * 128) * 8 + idx4] = v;\
                }                                                            \
            }                                                                \
        }                                                                    \
    }

// One GEMM pass: acc[m][0..31] += h_m(j) * W[j][0..31], j=0..63.
// W row read once per j from LDS, amortized over NPT nodes (4x fewer ds_reads).
#define MM_PASS(WMAT)                                                        \
    _Pragma("unroll 2")                                                      \
    for (int j = 0; j < 64; ++j) {                                           \
        float4 c4 = uvwc[j];                                                 \
        const float4* wr4 = (const float4*)(&WMAT[j * 32]);                  \
        float4 w[8];                                                         \
        _Pragma("unroll")                                                    \
        for (int q = 0; q < 8; ++q) w[q] = wr4[q];                           \
        _Pragma("unroll")                                                    \
        for (int m = 0; m < NPT; ++m) {                                      \
            float h = fmaxf(fmaf(in0[m], c4.x,                               \
                        fmaf(in1[m], c4.y, fmaf(in2[m], c4.z, c4.w))), 0.f); \
            _Pragma("unroll")                                                \
            for (int q = 0; q < 8; ++q) {                                    \
                acc[m][q * 4 + 0] = fmaf(h, w[q].x, acc[m][q * 4 + 0]);      \
                acc[m][q * 4 + 1] = fmaf(h, w[q].y, acc[m][q * 4 + 1]);      \
                acc[m][q * 4 + 2] = fmaf(h, w[q].z, acc[m][q * 4 + 2]);      \
                acc[m][q * 4 + 3] = fmaf(h, w[q].w, acc[m][q * 4 + 3]);      \
            }                                                                \
        }                                                                    \
    }

// =================== node A: 4 nodes/thread, 3 sequential passes ===========
__global__ __launch_bounds__(256) void node_a_kernel(
    const float* __restrict__ xa,
    const float* __restrict__ s_ba, const float* __restrict__ s_aa,
    const float* __restrict__ Wrel1, const float* __restrict__ Wroot1,
    const float* __restrict__ b1,
    const float* __restrict__ Wrel2, const float* __restrict__ Wroot2,
    const float* __restrict__ b2,
    uint16_t* __restrict__ ta0, uint16_t* __restrict__ ta2,
    float* __restrict__ outa) {
    __shared__ float4 uvwc[64];
    __shared__ float bbS[32];
    __shared__ float W0[2048], W2[2048], WrS[2048];
    __shared__ uint32_t stageU[4352];
    float* stageF = (float*)stageU;
    const int t = threadIdx.x;
    if (t < 64) {
        uvwc[t] = make_float4(Wrel1[64 + t], Wrel1[128 + t],
                              Wroot1[64 + t] + Wroot1[128 + t],
                              b1[64 + t] + b1[128 + t]);
    }
    if (t >= 64 && t < 96) bbS[t - 64] = b2[32 + (t - 64)] + b2[64 + (t - 64)];
    for (int i = t; i < 2048; i += 256) {
        W0[i]  = Wrel2[i];
        W2[i]  = Wrel2[4096 + i];
        WrS[i] = Wroot2[2048 + i] + Wroot2[4096 + i];
    }
    __syncthreads();

    const int base = blockIdx.x * (256 * NPT);
    float in0[NPT], in1[NPT], in2[NPT];     // sba, saa, x
#pragma unroll
    for (int m = 0; m < NPT; ++m) {
        int n = base + m * 256 + t;
        bool v = n < NA;
        in0[m] = v ? s_ba[n] : 0.f;
        in1[m] = v ? s_aa[n] : 0.f;
        in2[m] = v ? xa[n]   : 0.f;
    }

    float acc[NPT][32];
    // ---- pass 1: h*W0 -> ta0 (bf16) ----
#pragma unroll
    for (int m = 0; m < NPT; ++m)
#pragma unroll
        for (int o = 0; o < 32; ++o) acc[m][o] = 0.f;
    MM_PASS(W0)
    STAGE_BF16(acc, ta0, NA)

    // ---- pass 2: h*W2 -> ta2 (bf16) ----
#pragma unroll
    for (int m = 0; m < NPT; ++m)
#pragma unroll
        for (int o = 0; o < 32; ++o) acc[m][o] = 0.f;
    MM_PASS(W2)
    STAGE_BF16(acc, ta2, NA)

    // ---- pass 3: h*WrS + bias -> outa (f32) ----
#pragma unroll
    for (int m = 0; m < NPT; ++m)
#pragma unroll
        for (int o = 0; o < 32; ++o) acc[m][o] = bbS[o];
    MM_PASS(WrS)
    STAGE_F32(acc, outa, NA)
}

// =================== node B: 4 nodes/thread, 2 sequential passes ===========
__global__ __launch_bounds__(256) void node_b_kernel(
    const float* __restrict__ xb, const float* __restrict__ s_ab,
    const float* __restrict__ Wrel1, const float* __restrict__ Wroot1,
    const float* __restrict__ b1,
    const float* __restrict__ Wrel2, const float* __restrict__ Wroot2,
    const float* __restrict__ b2,
    uint16_t* __restrict__ tb1, float* __restrict__ outb) {
    __shared__ float4 uvwc[64];
    __shared__ float bbS[32];
    __shared__ float W1[2048], WrS[2048];
    __shared__ uint32_t stageU[4352];
    float* stageF = (float*)stageU;
    const int t = threadIdx.x;
    if (t < 64) {
        // y-slot unused for B (in1 = 0)
        uvwc[t] = make_float4(Wrel1[t], 0.f, Wroot1[t], b1[t]);
    }
    if (t >= 64 && t < 96) bbS[t - 64] = b2[t - 64];
    for (int i = t; i < 2048; i += 256) {
        W1[i]  = Wrel2[2048 + i];
        WrS[i] = Wroot2[i];
    }
    __syncthreads();

    const int base = blockIdx.x * (256 * NPT);
    float in0[NPT], in1[NPT], in2[NPT];     // sab, 0, x
#pragma unroll
    for (int m = 0; m < NPT; ++m) {
        int n = base + m * 256 + t;
        bool v = n < NB;
        in0[m] = v ? s_ab[n] : 0.f;
        in1[m] = 0.f;
        in2[m] = v ? xb[n] : 0.f;
    }

    float acc[NPT][32];
    // ---- pass 1: h*W1 -> tb1 (bf16) ----
#pragma unroll
    for (int m = 0; m < NPT; ++m)
#pragma unroll
        for (int o = 0; o < 32; ++o) acc[m][o] = 0.f;
    MM_PASS(W1)
    STAGE_BF16(acc, tb1, NB)

    // ---- pass 2: h*WrS + bias -> outb (f32) ----
#pragma unroll
    for (int m = 0; m < NPT; ++m)
#pragma unroll
        for (int o = 0; o < 32; ++o) acc[m][o] = bbS[o];
    MM_PASS(WrS)
    STAGE_F32(acc, outb, NB)
}

extern "C" void kernel_launch(void* const* d_in, const int* in_sizes, int n_in,
                              void* d_out, int out_size, void* d_ws, size_t ws_size,
                              hipStream_t stream) {
    const float* x_a    = (const float*)d_in[0];
    const float* x_b    = (const float*)d_in[1];
    const int*   ei_ab  = (const int*)d_in[2];
    const int*   ei_ba  = (const int*)d_in[3];
    const int*   ei_aa  = (const int*)d_in[4];
    const float* Wrel1  = (const float*)d_in[5];
    const float* Wroot1 = (const float*)d_in[6];
    const float* b1     = (const float*)d_in[7];
    const float* Wrel2  = (const float*)d_in[8];
    const float* Wroot2 = (const float*)d_in[9];
    const float* b2     = (const float*)d_in[10];

    float* outa = (float*)d_out;                       // [NA,32]
    float* outb = (float*)d_out + (size_t)NA * 32;     // [NB,32]

    char* ws = (char*)d_ws;
    // Layout (bytes):
    uint32_t* buck_a   = (uint32_t*)(ws);                    // 3907*704*4  = 11,002,112
    uint32_t* buck_b   = (uint32_t*)(ws + 11002112);         // 3907*400*4  =  6,251,200
    float*    agg_ba   = (float*)(ws + 17253312);            // NA floats   =  2,000,000
    float*    agg_aa   = (float*)(ws + 19253312);            // NA floats
    float*    agg_ab   = (float*)(ws + 21253312);            // NB floats
    uint16_t* ta0      = (uint16_t*)(ws + 23253312);         // NA*32 bf16  = 32,000,000
    uint16_t* ta2      = (uint16_t*)(ws + 55253312);         // NA*32 bf16
    uint16_t* tb1      = (uint16_t*)(ws + 87253312);         // NB*32 bf16
    uint16_t* start16_a= (uint16_t*)(ws + 119253312);        // 3907*128 u16 = 1,000,192
    uint16_t* start16_b= (uint16_t*)(ws + 120253504);        // 3907*128 u16
    uint16_t* ktot_a   = (uint16_t*)(ws + 121253696);        // 3907 u16 (pad 8192)
    uint16_t* ktot_b   = (uint16_t*)(ws + 121261888);        // 3907 u16 (pad 8192)
    int*      cnt_a    = (int*)(ws + 121270080);             // 8*3907 int = 125,024
    int*      cnt_b    = (int*)(ws + 121395104);             // 8*3907 int
    int*      ocnt     = (int*)(ws + 121520128);             // 1 int (+4 pad)
    uint2*    oflow    = (uint2*)(ws + 121520136);           // 4096 uint2 = 32,768
    if (ws_size < 121560000) return;  // need ~121.56 MB scratch

    // zero cnt_a, cnt_b, ocnt (one contiguous span)
    hipMemsetAsync((char*)cnt_a, 0, 125024 + 125024 + 8, stream);

    dim3 blk(256);
    int egrid = (3 * EE + 255) / 256;
    bucket_scatter<<<egrid, blk, 0, stream>>>(ei_ab, ei_ba, ei_aa, cnt_a, cnt_b,
                                              buck_a, buck_b, ocnt, oflow);

    sort_agg<<<dim3(NBUCK, 2), blk, 0, stream>>>(cnt_a, cnt_b, buck_a, buck_b,
                                                 x_a, x_b, agg_ba, agg_aa, agg_ab,
                                                 start16_a, start16_b,
                                                 ktot_a, ktot_b);
    oflow_agg<<<1, blk, 0, stream>>>(ocnt, oflow, x_a, x_b, agg_ba, agg_aa, agg_ab);

    int ngrid = (NA + 256 * NPT - 1) / (256 * NPT);   // 489
    node_a_kernel<<<ngrid, blk, 0, stream>>>(x_a, agg_ba, agg_aa, Wrel1, Wroot1,
                                             b1, Wrel2, Wroot2, b2, ta0, ta2, outa);
    node_b_kernel<<<ngrid, blk, 0, stream>>>(x_b, agg_ab, Wrel1, Wroot1, b1,
                                             Wrel2, Wroot2, b2, tb1, outb);

    int ggrid = (int)(((size_t)(NA + NB) * 8) / 256);  // 31250 exact
    gather_out<<<ggrid, blk, 0, stream>>>(ktot_a, ktot_b, start16_a, start16_b,
                                          buck_a, buck_b, ta0, ta2, tb1,
                                          outa, outb);
    oflow_out<<<1, blk, 0, stream>>>(ocnt, oflow, ta0, ta2, tb1, outa, outb);
}